// Round 11
// baseline (867.757 us; speedup 1.0000x reference)
//
#include <hip/hip_runtime.h>

#define NN 50000
#define NE 1200000
#define CCH 64
#define NLAYER 8
#define HID 128
#define NG 128
#define BN_EPS 1e-5f
#define SCAN_NB ((NN + 255) / 256)   // 196 blocks / buckets
#define EDGE_CHUNK 8192              // edges per bucket_scatter block

// ---- workspace layout (offsets in floats) ----
// [stats | pooled | counts | gcur | deg] <- zeroed by one memsetAsync
enum : size_t {
  OFF_STATS  = 0,
  OFF_POOLED = 1152,
  OFF_COUNTS = 9344,
  OFF_GCUR   = 9472,       // 196 bucket cursors (ints)
  OFF_DEG    = 9728,       // int[N] (zeroed; counts real in-edges only)
  MEMSET_F   = 59728,
  OFF_DIS    = 59728,
  OFF_OFFS   = 109728,     // N+1 (+pad)
  OFF_PART   = 159732,     // 256 block partials
  OFF_CSRSRC = 159988,     // ushort[E] (src < 65536)
  OFF_H      = 759988,     // float[N*64]
  OFF_HW     = 3959988,    // ushort[4][N][16] (bf16 channel slabs); staging aliases
  WS_FLOATS  = 5559988
};

__device__ __forceinline__ float bf2f(unsigned int hs) {
  union { unsigned int u; float f; } c; c.u = hs << 16; return c.f;
}
__device__ __forceinline__ unsigned int f2bf(float x) {
  union { float f; unsigned int u; } c; c.f = x;
  return (c.u + 0x7fffu + ((c.u >> 16) & 1u)) >> 16;  // RNE
}

__global__ void count_deg_kernel(const int* __restrict__ ei, int* __restrict__ deg) {
  int e = blockIdx.x * blockDim.x + threadIdx.x;
  if (e < NE) atomicAdd(&deg[ei[NE + e]], 1);
}

// Per-block exclusive scan of deg (real edges); dis = rsqrt(deg+1) (self-loop).
__global__ __launch_bounds__(256) void scan_blocks_kernel(const int* __restrict__ deg,
    int* __restrict__ offs, int* __restrict__ partials, float* __restrict__ dis) {
  int i = blockIdx.x * 256 + threadIdx.x;
  int v = 0;
  if (i < NN) {
    int d = deg[i];
    v = d;
    dis[i] = rsqrtf((float)(d + 1));
  }
  __shared__ int sm[256];
  sm[threadIdx.x] = v;
  __syncthreads();
  for (int d = 1; d < 256; d <<= 1) {
    int add = (threadIdx.x >= d) ? sm[threadIdx.x - d] : 0;
    __syncthreads();
    sm[threadIdx.x] += add;
    __syncthreads();
  }
  if (i < NN) offs[i] = sm[threadIdx.x] - v;  // exclusive within block
  if (threadIdx.x == 255) partials[blockIdx.x] = sm[255];
}

__global__ __launch_bounds__(256) void scan_carry_kernel(int* __restrict__ partials) {
  int t = threadIdx.x;
  int v = (t < SCAN_NB) ? partials[t] : 0;
  __shared__ int sm[256];
  sm[t] = v;
  __syncthreads();
  for (int d = 1; d < 256; d <<= 1) {
    int add = (t >= d) ? sm[t - d] : 0;
    __syncthreads();
    sm[t] += add;
    __syncthreads();
  }
  if (t < SCAN_NB) partials[t] = sm[t] - v;  // exclusive carry per block
}

__global__ __launch_bounds__(256) void scan_apply_kernel(const int* __restrict__ partials,
    int* __restrict__ offs) {
  int i = blockIdx.x * 256 + threadIdx.x;
  if (i < NN) offs[i] += partials[blockIdx.x];
  if (i == 0) offs[NN] = NE;
}

// ---- CSR build phase A: bucket edges by dst>>8 into staging (packed u32).
__global__ __launch_bounds__(256) void bucket_scatter_kernel(const int* __restrict__ ei,
    const int* __restrict__ offs, int* __restrict__ gcur, unsigned int* __restrict__ staging) {
  __shared__ int bcnt[SCAN_NB];
  __shared__ int bbase[SCAN_NB];
  int tid = threadIdx.x;
  int lo = blockIdx.x * EDGE_CHUNK;
  int hi = lo + EDGE_CHUNK; if (hi > NE) hi = NE;
  for (int b = tid; b < SCAN_NB; b += 256) bcnt[b] = 0;
  __syncthreads();
  for (int e = lo + tid; e < hi; e += 256)
    atomicAdd(&bcnt[ei[NE + e] >> 8], 1);
  __syncthreads();
  for (int b = tid; b < SCAN_NB; b += 256) {
    int c = bcnt[b];
    bbase[b] = c ? (offs[b << 8] + atomicAdd(&gcur[b], c)) : 0;
    bcnt[b] = 0;
  }
  __syncthreads();
  for (int e = lo + tid; e < hi; e += 256) {
    int src = ei[e], dst = ei[NE + e];
    int b = dst >> 8;
    int p = bbase[b] + atomicAdd(&bcnt[b], 1);
    staging[p] = ((unsigned int)(dst & 255) << 16) | (unsigned int)src;
  }
}

// ---- CSR build phase B: one block per bucket; LDS cursors; ushort placement.
__global__ __launch_bounds__(256) void bucket_fill_kernel(const unsigned int* __restrict__ staging,
    const int* __restrict__ offs, unsigned short* __restrict__ csr_src) {
  __shared__ int ncur[256];
  int b = blockIdx.x;
  int nodeBase = b << 8;
  int tid = threadIdx.x;
  int nHi = nodeBase + 256; if (nHi > NN) nHi = NN;
  int nLoc = nHi - nodeBase;
  if (tid < nLoc) ncur[tid] = offs[nodeBase + tid];
  __syncthreads();
  int r0 = offs[nodeBase], r1 = offs[nHi];
  for (int e = r0 + tid; e < r1; e += 256) {
    unsigned int v = staging[e];
    int p = atomicAdd(&ncur[v >> 16], 1);
    csr_src[p] = (unsigned short)(v & 0xffffu);
  }
}

// h = emb[x]; also accumulate BN stats for layer 0
__global__ __launch_bounds__(256) void embed_stats_kernel(const int* __restrict__ x,
    const float* __restrict__ emb, float* __restrict__ h, float* __restrict__ stats0) {
  int c = threadIdx.x & 63;
  int wave = (blockIdx.x * blockDim.x + threadIdx.x) >> 6;
  int nw = (gridDim.x * blockDim.x) >> 6;
  float ls = 0.f, lq = 0.f;
  for (int i = wave; i < NN; i += nw) {
    float v = emb[x[i] * CCH + c];
    h[(size_t)i * CCH + c] = v;
    ls += v; lq += v * v;
  }
  __shared__ float s1[256], s2[256];
  s1[threadIdx.x] = ls; s2[threadIdx.x] = lq;
  __syncthreads();
  if (threadIdx.x < 64) {
    float a = s1[threadIdx.x] + s1[threadIdx.x + 64] + s1[threadIdx.x + 128] + s1[threadIdx.x + 192];
    float b = s2[threadIdx.x] + s2[threadIdx.x + 64] + s2[threadIdx.x + 128] + s2[threadIdx.x + 192];
    atomicAdd(&stats0[c], a);
    atomicAdd(&stats0[64 + c], b);
  }
}

// Fused BN-fold + GEMM: hw' = bf16(((h-m)*rstd*gamma+beta) @ W * dis[node]),
// written in channel-slab layout: hwb[slab][node][16ch], slab = ch/16.
__global__ __launch_bounds__(256) void gemm_kernel(const float* __restrict__ h,
    const float* __restrict__ W, const float* __restrict__ gamma,
    const float* __restrict__ beta, const float* __restrict__ stats,
    const float* __restrict__ dis, unsigned short* __restrict__ hwb) {
  __shared__ float Ws[64 * 64];
  __shared__ float HsT[64 * 133];
  __shared__ float sm_a[64], sm_b2[64], sm_bias2[64];
  __shared__ float sm_part[4][64];
  int tid = threadIdx.x;
  if (tid < 64) {
    float inv_n = 1.0f / (float)NN;
    float m = stats[tid] * inv_n;
    float var = stats[64 + tid] * inv_n - m * m;
    float rstd = rsqrtf(var + BN_EPS);
    float av = gamma[tid] * rstd;
    sm_a[tid] = av;
    sm_b2[tid] = beta[tid] - m * av;
  }
  __syncthreads();
  int nodeBase = blockIdx.x * 128;
  for (int idx = tid; idx < 4096; idx += 256) Ws[idx] = sm_a[idx >> 6] * W[idx];
  for (int idx = tid; idx < 8192; idx += 256) {
    int node = idx >> 6, c = idx & 63;
    int gn = nodeBase + node;
    float v = (gn < NN) ? h[(size_t)gn * CCH + c] : 0.f;
    HsT[c * 133 + node] = v;
  }
  {  // bias2[j] = sum_k b2[k]*W[k][j], k-split over 4 groups of 16
    int j = tid & 63, kg = tid >> 6;
    float s = 0.f;
#pragma unroll
    for (int k = kg * 16; k < kg * 16 + 16; ++k) s += sm_b2[k] * W[k * 64 + j];
    sm_part[kg][j] = s;
  }
  __syncthreads();
  if (tid < 64)
    sm_bias2[tid] = sm_part[0][tid] + sm_part[1][tid] + sm_part[2][tid] + sm_part[3][tid];
  __syncthreads();
  int tc = tid & 15;   // channels tc*4..+3
  int tr = tid >> 4;   // nodes tr*8..+7
  float4 bb = *(const float4*)&sm_bias2[tc * 4];
  float acc[8][4];
#pragma unroll
  for (int i = 0; i < 8; ++i) { acc[i][0] = bb.x; acc[i][1] = bb.y; acc[i][2] = bb.z; acc[i][3] = bb.w; }
#pragma unroll 2
  for (int k = 0; k < 64; ++k) {
    float4 wv = *(const float4*)&Ws[k * 64 + tc * 4];
    float4 h0 = *(const float4*)&HsT[k * 133 + tr * 8];
    float4 h1 = *(const float4*)&HsT[k * 133 + tr * 8 + 4];
    float hv[8] = {h0.x, h0.y, h0.z, h0.w, h1.x, h1.y, h1.z, h1.w};
    float wl[4] = {wv.x, wv.y, wv.z, wv.w};
#pragma unroll
    for (int i = 0; i < 8; ++i)
#pragma unroll
      for (int j = 0; j < 4; ++j) acc[i][j] = fmaf(hv[i], wl[j], acc[i][j]);
  }
  unsigned short* slabp = hwb + (size_t)(tc >> 2) * NN * 16;
  int coff = (tc & 3) * 4;
#pragma unroll
  for (int i = 0; i < 8; ++i) {
    int gn = nodeBase + tr * 8 + i;
    if (gn < NN) {
      float dv = dis[gn];
      uint2 o;
      o.x = f2bf(acc[i][0] * dv) | (f2bf(acc[i][1] * dv) << 16);
      o.y = f2bf(acc[i][2] * dv) | (f2bf(acc[i][3] * dv) << 16);
      *(uint2*)&slabp[(size_t)gn * 16 + coff] = o;
    }
  }
}

__device__ __forceinline__ void acc_u2(float4& a, uint2 g) {
  a.x += bf2f(g.x & 0xffffu); a.y += bf2f(g.x >> 16);
  a.z += bf2f(g.y & 0xffffu); a.w += bf2f(g.y >> 16);
}
__device__ __forceinline__ void red4(float4& a) {
  a.x += __shfl_xor(a.x, 4);  a.y += __shfl_xor(a.y, 4);
  a.z += __shfl_xor(a.z, 4);  a.w += __shfl_xor(a.w, 4);
  a.x += __shfl_xor(a.x, 8);  a.y += __shfl_xor(a.y, 8);
  a.z += __shfl_xor(a.z, 8);  a.w += __shfl_xor(a.w, 8);
  a.x += __shfl_xor(a.x, 16); a.y += __shfl_xor(a.y, 16);
  a.z += __shfl_xor(a.z, 16); a.w += __shfl_xor(a.w, 16);
  a.x += __shfl_xor(a.x, 32); a.y += __shfl_xor(a.y, 32);
  a.z += __shfl_xor(a.z, 32); a.w += __shfl_xor(a.w, 32);
}

// h = relu(h + conv_b + dis_i*(hw'_i + sum_in hw'_src)); fused BN stats.
// 4-way channel-slab split with XCD affinity (slab = blockIdx&3; 1.6MB slab
// is per-XCD L2 resident). 4 lanes/edge (uint2 = 8B), 16 edge-slots/instr.
// TWO nodes pipelined per iteration: 64 edges in flight on 2 indep chains.
__global__ __launch_bounds__(256) void aggregate_kernel(float* __restrict__ h,
    const unsigned short* __restrict__ hwb, const float* __restrict__ dis,
    const int* __restrict__ offs, const unsigned short* __restrict__ csr_src,
    const float* __restrict__ conv_b_l, float* __restrict__ stats_next) {
  int tid = threadIdx.x;
  int b = blockIdx.x;
  int slab = b & 3;                            // XCD = b&7; slab = XCD&3
  int subIdx = (b >> 3) * 2 + ((b >> 2) & 1);  // block index among those sharing slab
  int wid = subIdx * 4 + (tid >> 6);
  int nwSlab = (gridDim.x >> 2) * 4;           // waves per slab
  int chunk = (NN + nwSlab - 1) / nwSlab;
  int lo = wid * chunk;
  int hi = lo + chunk; if (hi > NN) hi = NN;
  int lane = tid & 63;
  int slot = lane >> 2;                        // edge slot 0..15
  int l = lane & 3;                            // channel quad within slab
  const unsigned short* slabp = hwb + (size_t)slab * NN * 16;
  float4 cb = ((const float4*)conv_b_l)[slab * 4 + l];
  float4 ls = {0.f, 0.f, 0.f, 0.f}, lq = {0.f, 0.f, 0.f, 0.f};
  int i = lo;
  for (; i + 2 <= hi; i += 2) {
    int e0a = offs[i], e1a = offs[i + 1], e1b = offs[i + 2];
    // first 32 edges of node A and node B, issued together (4 csr + 4 gathers)
    int iA0 = e0a + slot, iA1 = e0a + 16 + slot;
    int iB0 = e1a + slot, iB1 = e1a + 16 + slot;
    int okA0 = iA0 < e1a, okA1 = iA1 < e1a;
    int okB0 = iB0 < e1b, okB1 = iB1 < e1b;
    int sA0 = csr_src[okA0 ? iA0 : 0];
    int sA1 = csr_src[okA1 ? iA1 : 0];
    int sB0 = csr_src[okB0 ? iB0 : 0];
    int sB1 = csr_src[okB1 ? iB1 : 0];
    uint2 gA0 = *(const uint2*)&slabp[(size_t)sA0 * 16 + 4 * l];
    uint2 gA1 = *(const uint2*)&slabp[(size_t)sA1 * 16 + 4 * l];
    uint2 gB0 = *(const uint2*)&slabp[(size_t)sB0 * 16 + 4 * l];
    uint2 gB1 = *(const uint2*)&slabp[(size_t)sB1 * 16 + 4 * l];
    uint2 selfA = *(const uint2*)&slabp[(size_t)i * 16 + 4 * l];
    uint2 selfB = *(const uint2*)&slabp[(size_t)(i + 1) * 16 + 4 * l];
    uint2 z; z.x = 0u; z.y = 0u;
    float4 aA = {0.f, 0.f, 0.f, 0.f}, aB = {0.f, 0.f, 0.f, 0.f};
    acc_u2(aA, okA0 ? gA0 : z); acc_u2(aA, okA1 ? gA1 : z);
    acc_u2(aB, okB0 ? gB0 : z); acc_u2(aB, okB1 ? gB1 : z);
    // residuals (deg > 32, ~5% of nodes)
    for (int base = e0a + 32; base < e1a; base += 32) {
      int j0 = base + slot, j1 = base + 16 + slot;
      int ok0 = j0 < e1a, ok1 = j1 < e1a;
      int s0 = csr_src[ok0 ? j0 : 0];
      int s1i = csr_src[ok1 ? j1 : 0];
      uint2 g0 = *(const uint2*)&slabp[(size_t)s0 * 16 + 4 * l];
      uint2 g1 = *(const uint2*)&slabp[(size_t)s1i * 16 + 4 * l];
      acc_u2(aA, ok0 ? g0 : z); acc_u2(aA, ok1 ? g1 : z);
    }
    for (int base = e1a + 32; base < e1b; base += 32) {
      int j0 = base + slot, j1 = base + 16 + slot;
      int ok0 = j0 < e1b, ok1 = j1 < e1b;
      int s0 = csr_src[ok0 ? j0 : 0];
      int s1i = csr_src[ok1 ? j1 : 0];
      uint2 g0 = *(const uint2*)&slabp[(size_t)s0 * 16 + 4 * l];
      uint2 g1 = *(const uint2*)&slabp[(size_t)s1i * 16 + 4 * l];
      acc_u2(aB, ok0 ? g0 : z); acc_u2(aB, ok1 ? g1 : z);
    }
    if (slot == 0) { acc_u2(aA, selfA); acc_u2(aB, selfB); }
    red4(aA); red4(aB);
    if (slot == 0) {
      float dA = dis[i], dB = dis[i + 1];
      float4 hvA = *(const float4*)&h[(size_t)i * 64 + slab * 16 + 4 * l];
      float4 hvB = *(const float4*)&h[(size_t)(i + 1) * 64 + slab * 16 + 4 * l];
      float4 vA, vB;
      vA.x = hvA.x + cb.x + dA * aA.x; vA.y = hvA.y + cb.y + dA * aA.y;
      vA.z = hvA.z + cb.z + dA * aA.z; vA.w = hvA.w + cb.w + dA * aA.w;
      vB.x = hvB.x + cb.x + dB * aB.x; vB.y = hvB.y + cb.y + dB * aB.y;
      vB.z = hvB.z + cb.z + dB * aB.z; vB.w = hvB.w + cb.w + dB * aB.w;
      vA.x = vA.x > 0.f ? vA.x : 0.f; vA.y = vA.y > 0.f ? vA.y : 0.f;
      vA.z = vA.z > 0.f ? vA.z : 0.f; vA.w = vA.w > 0.f ? vA.w : 0.f;
      vB.x = vB.x > 0.f ? vB.x : 0.f; vB.y = vB.y > 0.f ? vB.y : 0.f;
      vB.z = vB.z > 0.f ? vB.z : 0.f; vB.w = vB.w > 0.f ? vB.w : 0.f;
      *(float4*)&h[(size_t)i * 64 + slab * 16 + 4 * l] = vA;
      *(float4*)&h[(size_t)(i + 1) * 64 + slab * 16 + 4 * l] = vB;
      ls.x += vA.x + vB.x; ls.y += vA.y + vB.y; ls.z += vA.z + vB.z; ls.w += vA.w + vB.w;
      lq.x += vA.x * vA.x + vB.x * vB.x; lq.y += vA.y * vA.y + vB.y * vB.y;
      lq.z += vA.z * vA.z + vB.z * vB.z; lq.w += vA.w * vA.w + vB.w * vB.w;
    }
  }
  for (; i < hi; ++i) {  // odd tail node
    int e0a = offs[i], e1a = offs[i + 1];
    float4 aA = {0.f, 0.f, 0.f, 0.f};
    uint2 z; z.x = 0u; z.y = 0u;
    for (int base = e0a; base < e1a; base += 32) {
      int j0 = base + slot, j1 = base + 16 + slot;
      int ok0 = j0 < e1a, ok1 = j1 < e1a;
      int s0 = csr_src[ok0 ? j0 : 0];
      int s1i = csr_src[ok1 ? j1 : 0];
      uint2 g0 = *(const uint2*)&slabp[(size_t)s0 * 16 + 4 * l];
      uint2 g1 = *(const uint2*)&slabp[(size_t)s1i * 16 + 4 * l];
      acc_u2(aA, ok0 ? g0 : z); acc_u2(aA, ok1 ? g1 : z);
    }
    if (slot == 0) {
      uint2 selfA = *(const uint2*)&slabp[(size_t)i * 16 + 4 * l];
      acc_u2(aA, selfA);
    }
    red4(aA);
    if (slot == 0) {
      float dA = dis[i];
      float4 hvA = *(const float4*)&h[(size_t)i * 64 + slab * 16 + 4 * l];
      float4 vA;
      vA.x = hvA.x + cb.x + dA * aA.x; vA.y = hvA.y + cb.y + dA * aA.y;
      vA.z = hvA.z + cb.z + dA * aA.z; vA.w = hvA.w + cb.w + dA * aA.w;
      vA.x = vA.x > 0.f ? vA.x : 0.f; vA.y = vA.y > 0.f ? vA.y : 0.f;
      vA.z = vA.z > 0.f ? vA.z : 0.f; vA.w = vA.w > 0.f ? vA.w : 0.f;
      *(float4*)&h[(size_t)i * 64 + slab * 16 + 4 * l] = vA;
      ls.x += vA.x; ls.y += vA.y; ls.z += vA.z; ls.w += vA.w;
      lq.x += vA.x * vA.x; lq.y += vA.y * vA.y; lq.z += vA.z * vA.z; lq.w += vA.w * vA.w;
    }
  }
  __shared__ float4 s1[256], s2[256];
  s1[tid] = ls; s2[tid] = lq;
  __syncthreads();
  if (tid < 16) {  // this block covers 16 channels: slab*16 + tid
    int srcl = tid >> 2, comp = tid & 3;   // slot-0 lanes 0..3 of each wave
    float a = 0.f, bb = 0.f;
#pragma unroll
    for (int w = 0; w < 4; ++w) {
      float4 u1 = s1[w * 64 + srcl];
      float4 u2 = s2[w * 64 + srcl];
      float c1 = comp == 0 ? u1.x : comp == 1 ? u1.y : comp == 2 ? u1.z : u1.w;
      float c2 = comp == 0 ? u2.x : comp == 1 ? u2.y : comp == 2 ? u2.z : u2.w;
      a += c1; bb += c2;
    }
    atomicAdd(&stats_next[slab * 16 + tid], a);
    atomicAdd(&stats_next[64 + slab * 16 + tid], bb);
  }
}

// batch is SORTED: chunked per-wave register accumulation, one atomic per
// graph-boundary per channel.
__global__ __launch_bounds__(256) void pool_kernel(const float* __restrict__ h,
    const int* __restrict__ batch, float* __restrict__ pooled, float* __restrict__ counts) {
  int c = threadIdx.x & 63;
  int wid = (blockIdx.x * blockDim.x + threadIdx.x) >> 6;
  int nw = (gridDim.x * blockDim.x) >> 6;
  int chunk = (NN + nw - 1) / nw;
  int lo = wid * chunk;
  int hi = lo + chunk; if (hi > NN) hi = NN;
  if (lo >= hi) return;
  int g = batch[lo];
  float acc = 0.f, cnt = 0.f;
  for (int i = lo; i < hi; ++i) {
    int gi = batch[i];
    if (gi != g) {
      atomicAdd(&pooled[g * CCH + c], acc);
      if (c == 0) atomicAdd(&counts[g], cnt);
      g = gi; acc = 0.f; cnt = 0.f;
    }
    acc += h[(size_t)i * CCH + c];
    cnt += 1.f;
  }
  atomicAdd(&pooled[g * CCH + c], acc);
  if (c == 0) atomicAdd(&counts[g], cnt);
}

__global__ __launch_bounds__(128) void mlp_kernel(const float* __restrict__ pooled,
    const float* __restrict__ counts, const float* __restrict__ hid_w,
    const float* __restrict__ hid_b, const float* __restrict__ out_w,
    const float* __restrict__ out_b, float* __restrict__ out) {
  int g = blockIdx.x;
  int t = threadIdx.x;  // 128 threads
  __shared__ float p[64], hid[128];
  if (t < 64) {
    float cnt = counts[g];
    cnt = cnt > 1.f ? cnt : 1.f;
    p[t] = pooled[g * CCH + t] / cnt;
  }
  __syncthreads();
  float acc = hid_b[t];
  for (int k = 0; k < 64; ++k) acc = fmaf(p[k], hid_w[k * HID + t], acc);
  acc = acc > 0.f ? acc : 0.f;
  hid[t] = acc;
  __syncthreads();
  if (t < 64) {
    float o = out_b[t];
    for (int j = 0; j < 128; ++j) o = fmaf(hid[j], out_w[j * CCH + t], o);
    out[g * CCH + t] = o;
  }
}

extern "C" void kernel_launch(void* const* d_in, const int* in_sizes, int n_in,
                              void* d_out, int out_size, void* d_ws, size_t ws_size,
                              hipStream_t stream) {
  const int* x       = (const int*)d_in[0];
  const int* ei      = (const int*)d_in[1];
  const int* batch   = (const int*)d_in[2];
  const float* emb   = (const float*)d_in[3];
  const float* gamma = (const float*)d_in[4];
  const float* beta  = (const float*)d_in[5];
  const float* convw = (const float*)d_in[6];
  const float* convb = (const float*)d_in[7];
  const float* hid_w = (const float*)d_in[8];
  const float* hid_b = (const float*)d_in[9];
  const float* out_w = (const float*)d_in[10];
  const float* out_b = (const float*)d_in[11];
  float* out = (float*)d_out;

  float* ws     = (float*)d_ws;
  float* stats  = ws + OFF_STATS;
  float* pooled = ws + OFF_POOLED;
  float* counts = ws + OFF_COUNTS;
  int*   gcur   = (int*)(ws + OFF_GCUR);
  int*   deg    = (int*)(ws + OFF_DEG);
  float* dis    = ws + OFF_DIS;
  int*   offs   = (int*)(ws + OFF_OFFS);
  int*   part   = (int*)(ws + OFF_PART);
  unsigned short* csrsrc = (unsigned short*)(ws + OFF_CSRSRC);
  float* h      = ws + OFF_H;
  unsigned short* hwb = (unsigned short*)(ws + OFF_HW);
  unsigned int* staging = (unsigned int*)(ws + OFF_HW);  // aliases hwb (used before gemm)

  hipMemsetAsync(ws, 0, MEMSET_F * sizeof(float), stream);
  count_deg_kernel<<<(NE + 255) / 256, 256, 0, stream>>>(ei, deg);
  scan_blocks_kernel<<<SCAN_NB, 256, 0, stream>>>(deg, offs, part, dis);
  scan_carry_kernel<<<1, 256, 0, stream>>>(part);
  scan_apply_kernel<<<SCAN_NB, 256, 0, stream>>>(part, offs);
  bucket_scatter_kernel<<<(NE + EDGE_CHUNK - 1) / EDGE_CHUNK, 256, 0, stream>>>(ei, offs, gcur, staging);
  bucket_fill_kernel<<<SCAN_NB, 256, 0, stream>>>(staging, offs, csrsrc);
  embed_stats_kernel<<<512, 256, 0, stream>>>(x, emb, h, stats);

  for (int l = 0; l < NLAYER; ++l) {
    gemm_kernel<<<(NN + 127) / 128, 256, 0, stream>>>(h, convw + l * 4096,
                                                      gamma + l * 64, beta + l * 64,
                                                      stats + l * 128, dis, hwb);
    aggregate_kernel<<<2048, 256, 0, stream>>>(h, hwb, dis, offs, csrsrc,
                                               convb + l * 64, stats + (l + 1) * 128);
  }

  pool_kernel<<<128, 256, 0, stream>>>(h, batch, pooled, counts);
  mlp_kernel<<<NG, 128, 0, stream>>>(pooled, counts, hid_w, hid_b, out_w, out_b, out);
}

// Round 12
// 786.595 us; speedup vs baseline: 1.1032x; 1.1032x over previous
//
#include <hip/hip_runtime.h>

#define NN 50000
#define NE 1200000
#define CCH 64
#define NLAYER 8
#define HID 128
#define NG 128
#define BN_EPS 1e-5f
#define SCAN_NB ((NN + 255) / 256)   // 196 buckets
#define EDGE_CHUNK 8192              // edges per bucket_scatter block
#define BCAP 8064                    // staging capacity per bucket (mean 6144, +24 sigma)

// ---- workspace layout (offsets in floats) ----
// [stats | pooled | counts | gcur] <- zeroed by one memsetAsync
enum : size_t {
  OFF_STATS  = 0,
  OFF_POOLED = 1152,
  OFF_COUNTS = 9344,
  OFF_GCUR   = 9472,       // 196 bucket counters (ints)
  MEMSET_F   = 9728,
  OFF_DIS    = 9728,
  OFF_OFFS   = 59728,      // N+1 (+pad)
  OFF_PART   = 109732,     // 256 bucket starts (ints)
  OFF_CSRSRC = 109988,     // ushort[E]
  OFF_H      = 709988,     // float[N*64]
  OFF_HW     = 3909988,    // ushort[4][N][16] bf16 slabs; staging (uint[196*BCAP]) aliases
  WS_FLOATS  = 5509988
};

__device__ __forceinline__ float bf2f(unsigned int hs) {
  union { unsigned int u; float f; } c; c.u = hs << 16; return c.f;
}
__device__ __forceinline__ unsigned int f2bf(float x) {
  union { float f; unsigned int u; } c; c.f = x;
  return (c.u + 0x7fffu + ((c.u >> 16) & 1u)) >> 16;  // RNE
}

// ---- CSR build phase A: bucket edges by dst>>8 into fixed-capacity staging.
// Per-block LDS histogram + one global atomic per (block,bucket) range-grab.
__global__ __launch_bounds__(256) void bucket_scatter_kernel(const int* __restrict__ ei,
    int* __restrict__ gcur, unsigned int* __restrict__ staging) {
  __shared__ int bcnt[SCAN_NB];
  __shared__ int bbase[SCAN_NB];
  int tid = threadIdx.x;
  int lo = blockIdx.x * EDGE_CHUNK;
  int hi = lo + EDGE_CHUNK; if (hi > NE) hi = NE;
  for (int b = tid; b < SCAN_NB; b += 256) bcnt[b] = 0;
  __syncthreads();
  for (int e = lo + tid; e < hi; e += 256)
    atomicAdd(&bcnt[ei[NE + e] >> 8], 1);
  __syncthreads();
  for (int b = tid; b < SCAN_NB; b += 256) {
    int c = bcnt[b];
    bbase[b] = c ? (b * BCAP + atomicAdd(&gcur[b], c)) : 0;
    bcnt[b] = 0;
  }
  __syncthreads();
  for (int e = lo + tid; e < hi; e += 256) {
    int src = ei[e], dst = ei[NE + e];
    int b = dst >> 8;
    int p = bbase[b] + atomicAdd(&bcnt[b], 1);
    staging[p] = ((unsigned int)(dst & 255) << 16) | (unsigned int)src;
  }
}

// ---- CSR build phase B: exclusive scan of bucket totals (1 block).
__global__ __launch_bounds__(256) void bucket_scan_kernel(const int* __restrict__ gcur,
    int* __restrict__ bstart) {
  int t = threadIdx.x;
  int v = (t < SCAN_NB) ? gcur[t] : 0;
  __shared__ int sm[256];
  sm[t] = v;
  __syncthreads();
  for (int d = 1; d < 256; d <<= 1) {
    int add = (t >= d) ? sm[t - d] : 0;
    __syncthreads();
    sm[t] += add;
    __syncthreads();
  }
  if (t < SCAN_NB) bstart[t] = sm[t] - v;
}

// ---- CSR build phase C: per bucket — LDS degree histogram -> dis, LDS scan
// -> offs, LDS cursors -> csr_src placement. Fuses count_deg+scan+fill; all
// per-edge atomics are LDS-speed.
__global__ __launch_bounds__(256) void bucket_build_kernel(const unsigned int* __restrict__ staging,
    const int* __restrict__ gcur, const int* __restrict__ bstart,
    int* __restrict__ offs, float* __restrict__ dis, unsigned short* __restrict__ csr_src) {
  __shared__ int hcnt[256];
  __shared__ int sm[256];
  __shared__ int ncur[256];
  int b = blockIdx.x;
  int tid = threadIdx.x;
  int cnt = gcur[b];
  int base = bstart[b];
  const unsigned int* st = staging + (size_t)b * BCAP;
  hcnt[tid] = 0;
  __syncthreads();
  for (int e = tid; e < cnt; e += 256)
    atomicAdd(&hcnt[st[e] >> 16], 1);
  __syncthreads();
  int d = hcnt[tid];
  int node = (b << 8) + tid;
  if (node < NN) dis[node] = rsqrtf((float)(d + 1));  // +1 self-loop
  sm[tid] = d;
  __syncthreads();
  for (int s = 1; s < 256; s <<= 1) {
    int add = (tid >= s) ? sm[tid - s] : 0;
    __syncthreads();
    sm[tid] += add;
    __syncthreads();
  }
  int excl = sm[tid] - d;
  if (node < NN) offs[node] = base + excl;
  if (node == NN - 1) offs[NN] = NE;
  ncur[tid] = base + excl;
  __syncthreads();
  for (int e = tid; e < cnt; e += 256) {
    unsigned int v = st[e];
    int p = atomicAdd(&ncur[v >> 16], 1);
    csr_src[p] = (unsigned short)(v & 0xffffu);
  }
}

// h = emb[x]; also accumulate BN stats for layer 0
__global__ __launch_bounds__(256) void embed_stats_kernel(const int* __restrict__ x,
    const float* __restrict__ emb, float* __restrict__ h, float* __restrict__ stats0) {
  int c = threadIdx.x & 63;
  int wave = (blockIdx.x * blockDim.x + threadIdx.x) >> 6;
  int nw = (gridDim.x * blockDim.x) >> 6;
  float ls = 0.f, lq = 0.f;
  for (int i = wave; i < NN; i += nw) {
    float v = emb[x[i] * CCH + c];
    h[(size_t)i * CCH + c] = v;
    ls += v; lq += v * v;
  }
  __shared__ float s1[256], s2[256];
  s1[threadIdx.x] = ls; s2[threadIdx.x] = lq;
  __syncthreads();
  if (threadIdx.x < 64) {
    float a = s1[threadIdx.x] + s1[threadIdx.x + 64] + s1[threadIdx.x + 128] + s1[threadIdx.x + 192];
    float b = s2[threadIdx.x] + s2[threadIdx.x + 64] + s2[threadIdx.x + 128] + s2[threadIdx.x + 192];
    atomicAdd(&stats0[c], a);
    atomicAdd(&stats0[64 + c], b);
  }
}

// Fused BN-fold + GEMM: hw' = bf16(((h-m)*rstd*gamma+beta) @ W * dis[node]),
// written in channel-slab layout: hwb[slab][node][16ch], slab = ch/16.
__global__ __launch_bounds__(256) void gemm_kernel(const float* __restrict__ h,
    const float* __restrict__ W, const float* __restrict__ gamma,
    const float* __restrict__ beta, const float* __restrict__ stats,
    const float* __restrict__ dis, unsigned short* __restrict__ hwb) {
  __shared__ float Ws[64 * 64];
  __shared__ float HsT[64 * 133];
  __shared__ float sm_a[64], sm_b2[64], sm_bias2[64];
  __shared__ float sm_part[4][64];
  int tid = threadIdx.x;
  if (tid < 64) {
    float inv_n = 1.0f / (float)NN;
    float m = stats[tid] * inv_n;
    float var = stats[64 + tid] * inv_n - m * m;
    float rstd = rsqrtf(var + BN_EPS);
    float av = gamma[tid] * rstd;
    sm_a[tid] = av;
    sm_b2[tid] = beta[tid] - m * av;
  }
  __syncthreads();
  int nodeBase = blockIdx.x * 128;
  for (int idx = tid; idx < 4096; idx += 256) Ws[idx] = sm_a[idx >> 6] * W[idx];
  for (int idx = tid; idx < 8192; idx += 256) {
    int node = idx >> 6, c = idx & 63;
    int gn = nodeBase + node;
    float v = (gn < NN) ? h[(size_t)gn * CCH + c] : 0.f;
    HsT[c * 133 + node] = v;
  }
  {  // bias2[j] = sum_k b2[k]*W[k][j], k-split over 4 groups of 16
    int j = tid & 63, kg = tid >> 6;
    float s = 0.f;
#pragma unroll
    for (int k = kg * 16; k < kg * 16 + 16; ++k) s += sm_b2[k] * W[k * 64 + j];
    sm_part[kg][j] = s;
  }
  __syncthreads();
  if (tid < 64)
    sm_bias2[tid] = sm_part[0][tid] + sm_part[1][tid] + sm_part[2][tid] + sm_part[3][tid];
  __syncthreads();
  int tc = tid & 15;   // channels tc*4..+3
  int tr = tid >> 4;   // nodes tr*8..+7
  float4 bb = *(const float4*)&sm_bias2[tc * 4];
  float acc[8][4];
#pragma unroll
  for (int i = 0; i < 8; ++i) { acc[i][0] = bb.x; acc[i][1] = bb.y; acc[i][2] = bb.z; acc[i][3] = bb.w; }
#pragma unroll 2
  for (int k = 0; k < 64; ++k) {
    float4 wv = *(const float4*)&Ws[k * 64 + tc * 4];
    float4 h0 = *(const float4*)&HsT[k * 133 + tr * 8];
    float4 h1 = *(const float4*)&HsT[k * 133 + tr * 8 + 4];
    float hv[8] = {h0.x, h0.y, h0.z, h0.w, h1.x, h1.y, h1.z, h1.w};
    float wl[4] = {wv.x, wv.y, wv.z, wv.w};
#pragma unroll
    for (int i = 0; i < 8; ++i)
#pragma unroll
      for (int j = 0; j < 4; ++j) acc[i][j] = fmaf(hv[i], wl[j], acc[i][j]);
  }
  unsigned short* slabp = hwb + (size_t)(tc >> 2) * NN * 16;
  int coff = (tc & 3) * 4;
#pragma unroll
  for (int i = 0; i < 8; ++i) {
    int gn = nodeBase + tr * 8 + i;
    if (gn < NN) {
      float dv = dis[gn];
      uint2 o;
      o.x = f2bf(acc[i][0] * dv) | (f2bf(acc[i][1] * dv) << 16);
      o.y = f2bf(acc[i][2] * dv) | (f2bf(acc[i][3] * dv) << 16);
      *(uint2*)&slabp[(size_t)gn * 16 + coff] = o;
    }
  }
}

// h = relu(h + conv_b + dis_i*(hw'_i + sum_in hw'_src)); fused BN stats.
// ROUND-10 version (best measured): 4-way channel-slab + XCD affinity,
// 8 lanes/edge (4B), 32 edges in flight (4 octets). 20 VGPR, occ ~68%.
__global__ __launch_bounds__(256) void aggregate_kernel(float* __restrict__ h,
    const unsigned short* __restrict__ hwb, const float* __restrict__ dis,
    const int* __restrict__ offs, const unsigned short* __restrict__ csr_src,
    const float* __restrict__ conv_b_l, float* __restrict__ stats_next) {
  int tid = threadIdx.x;
  int b = blockIdx.x;
  int slab = b & 3;                            // XCD = b&7; slab = XCD&3
  int subIdx = (b >> 3) * 2 + ((b >> 2) & 1);  // block index among those sharing slab
  int wid = subIdx * 4 + (tid >> 6);
  int nwSlab = (gridDim.x >> 2) * 4;           // waves per slab
  int chunk = (NN + nwSlab - 1) / nwSlab;
  int lo = wid * chunk;
  int hi = lo + chunk; if (hi > NN) hi = NN;
  int lane = tid & 63;
  int slot = lane >> 3;                        // which edge of the octet
  int l = lane & 7;                            // channel pair within slab (16 ch)
  int cbase = slab * 16;
  const unsigned short* slabp = hwb + (size_t)slab * NN * 16;
  float2 cb = ((const float2*)conv_b_l)[slab * 8 + l];
  float ls0 = 0.f, ls1 = 0.f, lq0 = 0.f, lq1 = 0.f;
  for (int i = lo; i < hi; ++i) {
    float a0 = 0.f, a1 = 0.f;
    if (slot == 0) {  // self term (pre-scaled by dis_i)
      unsigned int sv = *(const unsigned int*)&slabp[(size_t)i * 16 + 2 * l];
      a0 = bf2f(sv & 0xffffu); a1 = bf2f(sv >> 16);
    }
    int e0 = offs[i], e1 = offs[i + 1];
    for (int base = e0; base < e1; base += 32) {
      int iA = base + slot, iB = iA + 8, iC = iA + 16, iD = iA + 24;
      int okA = iA < e1, okB = iB < e1, okC = iC < e1, okD = iD < e1;
      int sA = csr_src[okA ? iA : e1 - 1];
      int sB = csr_src[okB ? iB : e1 - 1];
      int sC = csr_src[okC ? iC : e1 - 1];
      int sD = csr_src[okD ? iD : e1 - 1];
      unsigned int uA = *(const unsigned int*)&slabp[(size_t)sA * 16 + 2 * l];
      unsigned int uB = *(const unsigned int*)&slabp[(size_t)sB * 16 + 2 * l];
      unsigned int uC = *(const unsigned int*)&slabp[(size_t)sC * 16 + 2 * l];
      unsigned int uD = *(const unsigned int*)&slabp[(size_t)sD * 16 + 2 * l];
      uA = okA ? uA : 0u;
      uB = okB ? uB : 0u;
      uC = okC ? uC : 0u;
      uD = okD ? uD : 0u;
      a0 += bf2f(uA & 0xffffu) + bf2f(uB & 0xffffu) + bf2f(uC & 0xffffu) + bf2f(uD & 0xffffu);
      a1 += bf2f(uA >> 16) + bf2f(uB >> 16) + bf2f(uC >> 16) + bf2f(uD >> 16);
    }
    a0 += __shfl_xor(a0, 8); a0 += __shfl_xor(a0, 16); a0 += __shfl_xor(a0, 32);
    a1 += __shfl_xor(a1, 8); a1 += __shfl_xor(a1, 16); a1 += __shfl_xor(a1, 32);
    if (slot == 0) {
      float2 hv = ((const float2*)h)[(size_t)i * 32 + slab * 8 + l];
      float d = dis[i];
      float v0 = hv.x + cb.x + d * a0;
      float v1 = hv.y + cb.y + d * a1;
      v0 = v0 > 0.f ? v0 : 0.f;
      v1 = v1 > 0.f ? v1 : 0.f;
      float2 o; o.x = v0; o.y = v1;
      ((float2*)h)[(size_t)i * 32 + slab * 8 + l] = o;
      ls0 += v0; lq0 += v0 * v0; ls1 += v1; lq1 += v1 * v1;
    }
  }
  __shared__ float2 s1[256], s2[256];
  float2 t1; t1.x = ls0; t1.y = ls1;
  float2 t2; t2.x = lq0; t2.y = lq1;
  s1[tid] = t1; s2[tid] = t2;
  __syncthreads();
  if (tid < 16) {  // this block covers 16 channels: cbase + tid
    int pair = tid >> 1, comp = tid & 1;   // slot-0 lanes 0..7 of each wave
    float a = 0.f, bb = 0.f;
#pragma unroll
    for (int w = 0; w < 4; ++w) {
      float2 u1 = s1[w * 64 + pair];
      float2 u2 = s2[w * 64 + pair];
      a += comp ? u1.y : u1.x;
      bb += comp ? u2.y : u2.x;
    }
    atomicAdd(&stats_next[cbase + tid], a);
    atomicAdd(&stats_next[64 + cbase + tid], bb);
  }
}

// batch is SORTED: chunked per-wave register accumulation, one atomic per
// graph-boundary per channel.
__global__ __launch_bounds__(256) void pool_kernel(const float* __restrict__ h,
    const int* __restrict__ batch, float* __restrict__ pooled, float* __restrict__ counts) {
  int c = threadIdx.x & 63;
  int wid = (blockIdx.x * blockDim.x + threadIdx.x) >> 6;
  int nw = (gridDim.x * blockDim.x) >> 6;
  int chunk = (NN + nw - 1) / nw;
  int lo = wid * chunk;
  int hi = lo + chunk; if (hi > NN) hi = NN;
  if (lo >= hi) return;
  int g = batch[lo];
  float acc = 0.f, cnt = 0.f;
  for (int i = lo; i < hi; ++i) {
    int gi = batch[i];
    if (gi != g) {
      atomicAdd(&pooled[g * CCH + c], acc);
      if (c == 0) atomicAdd(&counts[g], cnt);
      g = gi; acc = 0.f; cnt = 0.f;
    }
    acc += h[(size_t)i * CCH + c];
    cnt += 1.f;
  }
  atomicAdd(&pooled[g * CCH + c], acc);
  if (c == 0) atomicAdd(&counts[g], cnt);
}

__global__ __launch_bounds__(128) void mlp_kernel(const float* __restrict__ pooled,
    const float* __restrict__ counts, const float* __restrict__ hid_w,
    const float* __restrict__ hid_b, const float* __restrict__ out_w,
    const float* __restrict__ out_b, float* __restrict__ out) {
  int g = blockIdx.x;
  int t = threadIdx.x;  // 128 threads
  __shared__ float p[64], hid[128];
  if (t < 64) {
    float cnt = counts[g];
    cnt = cnt > 1.f ? cnt : 1.f;
    p[t] = pooled[g * CCH + t] / cnt;
  }
  __syncthreads();
  float acc = hid_b[t];
  for (int k = 0; k < 64; ++k) acc = fmaf(p[k], hid_w[k * HID + t], acc);
  acc = acc > 0.f ? acc : 0.f;
  hid[t] = acc;
  __syncthreads();
  if (t < 64) {
    float o = out_b[t];
    for (int j = 0; j < 128; ++j) o = fmaf(hid[j], out_w[j * CCH + t], o);
    out[g * CCH + t] = o;
  }
}

extern "C" void kernel_launch(void* const* d_in, const int* in_sizes, int n_in,
                              void* d_out, int out_size, void* d_ws, size_t ws_size,
                              hipStream_t stream) {
  const int* x       = (const int*)d_in[0];
  const int* ei      = (const int*)d_in[1];
  const int* batch   = (const int*)d_in[2];
  const float* emb   = (const float*)d_in[3];
  const float* gamma = (const float*)d_in[4];
  const float* beta  = (const float*)d_in[5];
  const float* convw = (const float*)d_in[6];
  const float* convb = (const float*)d_in[7];
  const float* hid_w = (const float*)d_in[8];
  const float* hid_b = (const float*)d_in[9];
  const float* out_w = (const float*)d_in[10];
  const float* out_b = (const float*)d_in[11];
  float* out = (float*)d_out;

  float* ws     = (float*)d_ws;
  float* stats  = ws + OFF_STATS;
  float* pooled = ws + OFF_POOLED;
  float* counts = ws + OFF_COUNTS;
  int*   gcur   = (int*)(ws + OFF_GCUR);
  float* dis    = ws + OFF_DIS;
  int*   offs   = (int*)(ws + OFF_OFFS);
  int*   bstart = (int*)(ws + OFF_PART);
  unsigned short* csrsrc = (unsigned short*)(ws + OFF_CSRSRC);
  float* h      = ws + OFF_H;
  unsigned short* hwb = (unsigned short*)(ws + OFF_HW);
  unsigned int* staging = (unsigned int*)(ws + OFF_HW);  // aliases hwb (used before gemm)

  hipMemsetAsync(ws, 0, MEMSET_F * sizeof(float), stream);
  bucket_scatter_kernel<<<(NE + EDGE_CHUNK - 1) / EDGE_CHUNK, 256, 0, stream>>>(ei, gcur, staging);
  bucket_scan_kernel<<<1, 256, 0, stream>>>(gcur, bstart);
  bucket_build_kernel<<<SCAN_NB, 256, 0, stream>>>(staging, gcur, bstart, offs, dis, csrsrc);
  embed_stats_kernel<<<512, 256, 0, stream>>>(x, emb, h, stats);

  for (int l = 0; l < NLAYER; ++l) {
    gemm_kernel<<<(NN + 127) / 128, 256, 0, stream>>>(h, convw + l * 4096,
                                                      gamma + l * 64, beta + l * 64,
                                                      stats + l * 128, dis, hwb);
    aggregate_kernel<<<2048, 256, 0, stream>>>(h, hwb, dis, offs, csrsrc,
                                               convb + l * 64, stats + (l + 1) * 128);
  }

  pool_kernel<<<128, 256, 0, stream>>>(h, batch, pooled, counts);
  mlp_kernel<<<NG, 128, 0, stream>>>(pooled, counts, hid_w, hid_b, out_w, out_b, out);
}

// Round 13
// 748.956 us; speedup vs baseline: 1.1586x; 1.0503x over previous
//
#include <hip/hip_runtime.h>

#define NN 50000
#define NE 1200000
#define CCH 64
#define NLAYER 8
#define HID 128
#define NG 128
#define BN_EPS 1e-5f
#define SCAN_NB ((NN + 255) / 256)   // 196 buckets
#define EDGE_CHUNK 8192              // edges per bucket_scatter block
#define BCAP 8064                    // staging capacity per bucket (mean 6144, +24 sigma)

// ---- workspace layout (offsets in floats) ----
// [stats | pooled | counts | gcur] <- zeroed by one memsetAsync
// h is now bf16 (ushort[N][64]) like hwb: halves h traffic in agg/gemm/embed/pool.
enum : size_t {
  OFF_STATS  = 0,
  OFF_POOLED = 1152,
  OFF_COUNTS = 9344,
  OFF_GCUR   = 9472,       // 196 bucket counters (ints)
  MEMSET_F   = 9728,
  OFF_DIS    = 9728,
  OFF_OFFS   = 59728,      // N+1 (+pad)
  OFF_PART   = 109732,     // 256 bucket starts (ints)
  OFF_CSRSRC = 109988,     // ushort[E]
  OFF_H      = 709988,     // ushort[N*64] bf16
  OFF_HW     = 2309988,    // ushort[4][N][16] bf16 slabs; staging (uint[196*BCAP]) aliases
  WS_FLOATS  = 3909988
};

__device__ __forceinline__ float bf2f(unsigned int hs) {
  union { unsigned int u; float f; } c; c.u = hs << 16; return c.f;
}
__device__ __forceinline__ unsigned int f2bf(float x) {
  union { float f; unsigned int u; } c; c.f = x;
  return (c.u + 0x7fffu + ((c.u >> 16) & 1u)) >> 16;  // RNE
}

// ---- CSR build phase A: bucket edges by dst>>8 into fixed-capacity staging.
__global__ __launch_bounds__(256) void bucket_scatter_kernel(const int* __restrict__ ei,
    int* __restrict__ gcur, unsigned int* __restrict__ staging) {
  __shared__ int bcnt[SCAN_NB];
  __shared__ int bbase[SCAN_NB];
  int tid = threadIdx.x;
  int lo = blockIdx.x * EDGE_CHUNK;
  int hi = lo + EDGE_CHUNK; if (hi > NE) hi = NE;
  for (int b = tid; b < SCAN_NB; b += 256) bcnt[b] = 0;
  __syncthreads();
  for (int e = lo + tid; e < hi; e += 256)
    atomicAdd(&bcnt[ei[NE + e] >> 8], 1);
  __syncthreads();
  for (int b = tid; b < SCAN_NB; b += 256) {
    int c = bcnt[b];
    bbase[b] = c ? (b * BCAP + atomicAdd(&gcur[b], c)) : 0;
    bcnt[b] = 0;
  }
  __syncthreads();
  for (int e = lo + tid; e < hi; e += 256) {
    int src = ei[e], dst = ei[NE + e];
    int b = dst >> 8;
    int p = bbase[b] + atomicAdd(&bcnt[b], 1);
    staging[p] = ((unsigned int)(dst & 255) << 16) | (unsigned int)src;
  }
}

// ---- CSR build phase B: exclusive scan of bucket totals (1 block).
__global__ __launch_bounds__(256) void bucket_scan_kernel(const int* __restrict__ gcur,
    int* __restrict__ bstart) {
  int t = threadIdx.x;
  int v = (t < SCAN_NB) ? gcur[t] : 0;
  __shared__ int sm[256];
  sm[t] = v;
  __syncthreads();
  for (int d = 1; d < 256; d <<= 1) {
    int add = (t >= d) ? sm[t - d] : 0;
    __syncthreads();
    sm[t] += add;
    __syncthreads();
  }
  if (t < SCAN_NB) bstart[t] = sm[t] - v;
}

// ---- CSR build phase C: per bucket — LDS degree histogram -> dis, LDS scan
// -> offs, LDS cursors -> csr_src placement.
__global__ __launch_bounds__(256) void bucket_build_kernel(const unsigned int* __restrict__ staging,
    const int* __restrict__ gcur, const int* __restrict__ bstart,
    int* __restrict__ offs, float* __restrict__ dis, unsigned short* __restrict__ csr_src) {
  __shared__ int hcnt[256];
  __shared__ int sm[256];
  __shared__ int ncur[256];
  int b = blockIdx.x;
  int tid = threadIdx.x;
  int cnt = gcur[b];
  int base = bstart[b];
  const unsigned int* st = staging + (size_t)b * BCAP;
  hcnt[tid] = 0;
  __syncthreads();
  for (int e = tid; e < cnt; e += 256)
    atomicAdd(&hcnt[st[e] >> 16], 1);
  __syncthreads();
  int d = hcnt[tid];
  int node = (b << 8) + tid;
  if (node < NN) dis[node] = rsqrtf((float)(d + 1));  // +1 self-loop
  sm[tid] = d;
  __syncthreads();
  for (int s = 1; s < 256; s <<= 1) {
    int add = (tid >= s) ? sm[tid - s] : 0;
    __syncthreads();
    sm[tid] += add;
    __syncthreads();
  }
  int excl = sm[tid] - d;
  if (node < NN) offs[node] = base + excl;
  if (node == NN - 1) offs[NN] = NE;
  ncur[tid] = base + excl;
  __syncthreads();
  for (int e = tid; e < cnt; e += 256) {
    unsigned int v = st[e];
    int p = atomicAdd(&ncur[v >> 16], 1);
    csr_src[p] = (unsigned short)(v & 0xffffu);
  }
}

// h = bf16(emb[x]); BN stats for layer 0 accumulated on the ROUNDED values
// (self-consistent with what downstream layers read).
__global__ __launch_bounds__(256) void embed_stats_kernel(const int* __restrict__ x,
    const float* __restrict__ emb, unsigned short* __restrict__ hb, float* __restrict__ stats0) {
  int c = threadIdx.x & 63;
  int wave = (blockIdx.x * blockDim.x + threadIdx.x) >> 6;
  int nw = (gridDim.x * blockDim.x) >> 6;
  float ls = 0.f, lq = 0.f;
  for (int i = wave; i < NN; i += nw) {
    float v = emb[x[i] * CCH + c];
    unsigned int r = f2bf(v);
    hb[(size_t)i * CCH + c] = (unsigned short)r;
    float vr = bf2f(r);
    ls += vr; lq += vr * vr;
  }
  __shared__ float s1[256], s2[256];
  s1[threadIdx.x] = ls; s2[threadIdx.x] = lq;
  __syncthreads();
  if (threadIdx.x < 64) {
    float a = s1[threadIdx.x] + s1[threadIdx.x + 64] + s1[threadIdx.x + 128] + s1[threadIdx.x + 192];
    float b = s2[threadIdx.x] + s2[threadIdx.x + 64] + s2[threadIdx.x + 128] + s2[threadIdx.x + 192];
    atomicAdd(&stats0[c], a);
    atomicAdd(&stats0[64 + c], b);
  }
}

// Fused BN-fold + GEMM: hw' = bf16(((h-m)*rstd*gamma+beta) @ W * dis[node]),
// h read as bf16 pairs (uint), expanded to fp32 in LDS for the FMA loop.
__global__ __launch_bounds__(256) void gemm_kernel(const unsigned short* __restrict__ hb,
    const float* __restrict__ W, const float* __restrict__ gamma,
    const float* __restrict__ beta, const float* __restrict__ stats,
    const float* __restrict__ dis, unsigned short* __restrict__ hwb) {
  __shared__ float Ws[64 * 64];
  __shared__ float HsT[64 * 133];
  __shared__ float sm_a[64], sm_b2[64], sm_bias2[64];
  __shared__ float sm_part[4][64];
  int tid = threadIdx.x;
  if (tid < 64) {
    float inv_n = 1.0f / (float)NN;
    float m = stats[tid] * inv_n;
    float var = stats[64 + tid] * inv_n - m * m;
    float rstd = rsqrtf(var + BN_EPS);
    float av = gamma[tid] * rstd;
    sm_a[tid] = av;
    sm_b2[tid] = beta[tid] - m * av;
  }
  __syncthreads();
  int nodeBase = blockIdx.x * 128;
  for (int idx = tid; idx < 4096; idx += 256) Ws[idx] = sm_a[idx >> 6] * W[idx];
  const unsigned int* h32 = (const unsigned int*)hb;  // [N][32] channel pairs
  for (int idx = tid; idx < 4096; idx += 256) {       // 128 nodes x 32 pairs
    int node = idx >> 5, cp = idx & 31;
    int gn = nodeBase + node;
    unsigned int u = (gn < NN) ? h32[(size_t)gn * 32 + cp] : 0u;
    HsT[(2 * cp) * 133 + node]     = bf2f(u & 0xffffu);
    HsT[(2 * cp + 1) * 133 + node] = bf2f(u >> 16);
  }
  {  // bias2[j] = sum_k b2[k]*W[k][j], k-split over 4 groups of 16
    int j = tid & 63, kg = tid >> 6;
    float s = 0.f;
#pragma unroll
    for (int k = kg * 16; k < kg * 16 + 16; ++k) s += sm_b2[k] * W[k * 64 + j];
    sm_part[kg][j] = s;
  }
  __syncthreads();
  if (tid < 64)
    sm_bias2[tid] = sm_part[0][tid] + sm_part[1][tid] + sm_part[2][tid] + sm_part[3][tid];
  __syncthreads();
  int tc = tid & 15;   // channels tc*4..+3
  int tr = tid >> 4;   // nodes tr*8..+7
  float4 bb = *(const float4*)&sm_bias2[tc * 4];
  float acc[8][4];
#pragma unroll
  for (int i = 0; i < 8; ++i) { acc[i][0] = bb.x; acc[i][1] = bb.y; acc[i][2] = bb.z; acc[i][3] = bb.w; }
#pragma unroll 2
  for (int k = 0; k < 64; ++k) {
    float4 wv = *(const float4*)&Ws[k * 64 + tc * 4];
    float4 h0 = *(const float4*)&HsT[k * 133 + tr * 8];
    float4 h1 = *(const float4*)&HsT[k * 133 + tr * 8 + 4];
    float hv[8] = {h0.x, h0.y, h0.z, h0.w, h1.x, h1.y, h1.z, h1.w};
    float wl[4] = {wv.x, wv.y, wv.z, wv.w};
#pragma unroll
    for (int i = 0; i < 8; ++i)
#pragma unroll
      for (int j = 0; j < 4; ++j) acc[i][j] = fmaf(hv[i], wl[j], acc[i][j]);
  }
  unsigned short* slabp = hwb + (size_t)(tc >> 2) * NN * 16;
  int coff = (tc & 3) * 4;
#pragma unroll
  for (int i = 0; i < 8; ++i) {
    int gn = nodeBase + tr * 8 + i;
    if (gn < NN) {
      float dv = dis[gn];
      uint2 o;
      o.x = f2bf(acc[i][0] * dv) | (f2bf(acc[i][1] * dv) << 16);
      o.y = f2bf(acc[i][2] * dv) | (f2bf(acc[i][3] * dv) << 16);
      *(uint2*)&slabp[(size_t)gn * 16 + coff] = o;
    }
  }
}

// h = relu(h + conv_b + dis_i*(hw'_i + sum_in hw'_src)) in bf16; fused BN
// stats on the ROUNDED values. Round-10 shape: 4-way channel-slab + XCD
// affinity, 8 lanes/edge, 32 edges in flight.
__global__ __launch_bounds__(256) void aggregate_kernel(unsigned int* __restrict__ h32,
    const unsigned short* __restrict__ hwb, const float* __restrict__ dis,
    const int* __restrict__ offs, const unsigned short* __restrict__ csr_src,
    const float* __restrict__ conv_b_l, float* __restrict__ stats_next) {
  int tid = threadIdx.x;
  int b = blockIdx.x;
  int slab = b & 3;                            // XCD = b&7; slab = XCD&3
  int subIdx = (b >> 3) * 2 + ((b >> 2) & 1);  // block index among those sharing slab
  int wid = subIdx * 4 + (tid >> 6);
  int nwSlab = (gridDim.x >> 2) * 4;           // waves per slab
  int chunk = (NN + nwSlab - 1) / nwSlab;
  int lo = wid * chunk;
  int hi = lo + chunk; if (hi > NN) hi = NN;
  int lane = tid & 63;
  int slot = lane >> 3;                        // which edge of the octet
  int l = lane & 7;                            // channel pair within slab (16 ch)
  int cbase = slab * 16;
  const unsigned short* slabp = hwb + (size_t)slab * NN * 16;
  float2 cb = ((const float2*)conv_b_l)[slab * 8 + l];
  float ls0 = 0.f, ls1 = 0.f, lq0 = 0.f, lq1 = 0.f;
  for (int i = lo; i < hi; ++i) {
    float a0 = 0.f, a1 = 0.f;
    if (slot == 0) {  // self term (pre-scaled by dis_i)
      unsigned int sv = *(const unsigned int*)&slabp[(size_t)i * 16 + 2 * l];
      a0 = bf2f(sv & 0xffffu); a1 = bf2f(sv >> 16);
    }
    int e0 = offs[i], e1 = offs[i + 1];
    for (int base = e0; base < e1; base += 32) {
      int iA = base + slot, iB = iA + 8, iC = iA + 16, iD = iA + 24;
      int okA = iA < e1, okB = iB < e1, okC = iC < e1, okD = iD < e1;
      int sA = csr_src[okA ? iA : e1 - 1];
      int sB = csr_src[okB ? iB : e1 - 1];
      int sC = csr_src[okC ? iC : e1 - 1];
      int sD = csr_src[okD ? iD : e1 - 1];
      unsigned int uA = *(const unsigned int*)&slabp[(size_t)sA * 16 + 2 * l];
      unsigned int uB = *(const unsigned int*)&slabp[(size_t)sB * 16 + 2 * l];
      unsigned int uC = *(const unsigned int*)&slabp[(size_t)sC * 16 + 2 * l];
      unsigned int uD = *(const unsigned int*)&slabp[(size_t)sD * 16 + 2 * l];
      uA = okA ? uA : 0u;
      uB = okB ? uB : 0u;
      uC = okC ? uC : 0u;
      uD = okD ? uD : 0u;
      a0 += bf2f(uA & 0xffffu) + bf2f(uB & 0xffffu) + bf2f(uC & 0xffffu) + bf2f(uD & 0xffffu);
      a1 += bf2f(uA >> 16) + bf2f(uB >> 16) + bf2f(uC >> 16) + bf2f(uD >> 16);
    }
    a0 += __shfl_xor(a0, 8); a0 += __shfl_xor(a0, 16); a0 += __shfl_xor(a0, 32);
    a1 += __shfl_xor(a1, 8); a1 += __shfl_xor(a1, 16); a1 += __shfl_xor(a1, 32);
    if (slot == 0) {
      unsigned int hu = h32[(size_t)i * 32 + slab * 8 + l];
      float d = dis[i];
      float v0 = bf2f(hu & 0xffffu) + cb.x + d * a0;
      float v1 = bf2f(hu >> 16)     + cb.y + d * a1;
      v0 = v0 > 0.f ? v0 : 0.f;
      v1 = v1 > 0.f ? v1 : 0.f;
      unsigned int b0 = f2bf(v0), b1 = f2bf(v1);
      h32[(size_t)i * 32 + slab * 8 + l] = b0 | (b1 << 16);
      float r0 = bf2f(b0), r1 = bf2f(b1);
      ls0 += r0; lq0 += r0 * r0; ls1 += r1; lq1 += r1 * r1;
    }
  }
  __shared__ float2 s1[256], s2[256];
  float2 t1; t1.x = ls0; t1.y = ls1;
  float2 t2; t2.x = lq0; t2.y = lq1;
  s1[tid] = t1; s2[tid] = t2;
  __syncthreads();
  if (tid < 16) {  // this block covers 16 channels: cbase + tid
    int pair = tid >> 1, comp = tid & 1;   // slot-0 lanes 0..7 of each wave
    float a = 0.f, bb = 0.f;
#pragma unroll
    for (int w = 0; w < 4; ++w) {
      float2 u1 = s1[w * 64 + pair];
      float2 u2 = s2[w * 64 + pair];
      a += comp ? u1.y : u1.x;
      bb += comp ? u2.y : u2.x;
    }
    atomicAdd(&stats_next[cbase + tid], a);
    atomicAdd(&stats_next[64 + cbase + tid], bb);
  }
}

// batch is SORTED: chunked per-wave register accumulation. h read as bf16.
__global__ __launch_bounds__(256) void pool_kernel(const unsigned short* __restrict__ hb,
    const int* __restrict__ batch, float* __restrict__ pooled, float* __restrict__ counts) {
  int c = threadIdx.x & 63;
  int wid = (blockIdx.x * blockDim.x + threadIdx.x) >> 6;
  int nw = (gridDim.x * blockDim.x) >> 6;
  int chunk = (NN + nw - 1) / nw;
  int lo = wid * chunk;
  int hi = lo + chunk; if (hi > NN) hi = NN;
  if (lo >= hi) return;
  int g = batch[lo];
  float acc = 0.f, cnt = 0.f;
  for (int i = lo; i < hi; ++i) {
    int gi = batch[i];
    if (gi != g) {
      atomicAdd(&pooled[g * CCH + c], acc);
      if (c == 0) atomicAdd(&counts[g], cnt);
      g = gi; acc = 0.f; cnt = 0.f;
    }
    acc += bf2f((unsigned int)hb[(size_t)i * CCH + c]);
    cnt += 1.f;
  }
  atomicAdd(&pooled[g * CCH + c], acc);
  if (c == 0) atomicAdd(&counts[g], cnt);
}

__global__ __launch_bounds__(128) void mlp_kernel(const float* __restrict__ pooled,
    const float* __restrict__ counts, const float* __restrict__ hid_w,
    const float* __restrict__ hid_b, const float* __restrict__ out_w,
    const float* __restrict__ out_b, float* __restrict__ out) {
  int g = blockIdx.x;
  int t = threadIdx.x;  // 128 threads
  __shared__ float p[64], hid[128];
  if (t < 64) {
    float cnt = counts[g];
    cnt = cnt > 1.f ? cnt : 1.f;
    p[t] = pooled[g * CCH + t] / cnt;
  }
  __syncthreads();
  float acc = hid_b[t];
  for (int k = 0; k < 64; ++k) acc = fmaf(p[k], hid_w[k * HID + t], acc);
  acc = acc > 0.f ? acc : 0.f;
  hid[t] = acc;
  __syncthreads();
  if (t < 64) {
    float o = out_b[t];
    for (int j = 0; j < 128; ++j) o = fmaf(hid[j], out_w[j * CCH + t], o);
    out[g * CCH + t] = o;
  }
}

extern "C" void kernel_launch(void* const* d_in, const int* in_sizes, int n_in,
                              void* d_out, int out_size, void* d_ws, size_t ws_size,
                              hipStream_t stream) {
  const int* x       = (const int*)d_in[0];
  const int* ei      = (const int*)d_in[1];
  const int* batch   = (const int*)d_in[2];
  const float* emb   = (const float*)d_in[3];
  const float* gamma = (const float*)d_in[4];
  const float* beta  = (const float*)d_in[5];
  const float* convw = (const float*)d_in[6];
  const float* convb = (const float*)d_in[7];
  const float* hid_w = (const float*)d_in[8];
  const float* hid_b = (const float*)d_in[9];
  const float* out_w = (const float*)d_in[10];
  const float* out_b = (const float*)d_in[11];
  float* out = (float*)d_out;

  float* ws     = (float*)d_ws;
  float* stats  = ws + OFF_STATS;
  float* pooled = ws + OFF_POOLED;
  float* counts = ws + OFF_COUNTS;
  int*   gcur   = (int*)(ws + OFF_GCUR);
  float* dis    = ws + OFF_DIS;
  int*   offs   = (int*)(ws + OFF_OFFS);
  int*   bstart = (int*)(ws + OFF_PART);
  unsigned short* csrsrc = (unsigned short*)(ws + OFF_CSRSRC);
  unsigned short* hb  = (unsigned short*)(ws + OFF_H);
  unsigned int*   h32 = (unsigned int*)(ws + OFF_H);
  unsigned short* hwb = (unsigned short*)(ws + OFF_HW);
  unsigned int* staging = (unsigned int*)(ws + OFF_HW);  // aliases hwb (used before gemm)

  hipMemsetAsync(ws, 0, MEMSET_F * sizeof(float), stream);
  bucket_scatter_kernel<<<(NE + EDGE_CHUNK - 1) / EDGE_CHUNK, 256, 0, stream>>>(ei, gcur, staging);
  bucket_scan_kernel<<<1, 256, 0, stream>>>(gcur, bstart);
  bucket_build_kernel<<<SCAN_NB, 256, 0, stream>>>(staging, gcur, bstart, offs, dis, csrsrc);
  embed_stats_kernel<<<512, 256, 0, stream>>>(x, emb, hb, stats);

  for (int l = 0; l < NLAYER; ++l) {
    gemm_kernel<<<(NN + 127) / 128, 256, 0, stream>>>(hb, convw + l * 4096,
                                                      gamma + l * 64, beta + l * 64,
                                                      stats + l * 128, dis, hwb);
    aggregate_kernel<<<2048, 256, 0, stream>>>(h32, hwb, dis, offs, csrsrc,
                                               convb + l * 64, stats + (l + 1) * 128);
  }

  pool_kernel<<<128, 256, 0, stream>>>(hb, batch, pooled, counts);
  mlp_kernel<<<NG, 128, 0, stream>>>(pooled, counts, hid_w, hid_b, out_w, out_b, out);
}